// Round 4
// baseline (2171.995 us; speedup 1.0000x reference)
//
#include <hip/hip_runtime.h>

typedef _Float16 half8 __attribute__((ext_vector_type(8)));
typedef float f32x4 __attribute__((ext_vector_type(4)));

union H8U { unsigned long long u[2]; half8 v; unsigned short s[8]; };

__device__ __forceinline__ float fast_sigmoid(float v) {
  return 1.0f / (1.0f + __expf(-v));
}
__device__ __forceinline__ float fast_tanh(float v) {
  return 2.0f / (1.0f + __expf(-2.0f * v)) - 1.0f;
}

#define AL(p)    __hip_atomic_load((p), __ATOMIC_RELAXED, __HIP_MEMORY_SCOPE_AGENT)
#define AS(p, x) __hip_atomic_store((p), (x), __ATOMIC_RELAXED, __HIP_MEMORY_SCOPE_AGENT)
// LDS frag-index swizzle: kills 8-way bank conflicts on staging writes while
// keeping wave-wide b128 reads a per-8-group lane permutation (still optimal).
#define SWZ(i) ((i) ^ (((i) >> 6) & 7))

// ---------------------------------------------------------------------------
// prep: build frag-ordered f16 copies of W1, W2.
// Frag layout (B operand of mfma_f32_16x16x32_f16): flat index
// ((ct*8 + ks)*64 + lane)*8 + s holds W[k = ks*32+(lane>>4)*8+s][col = ct*16+(lane&15)]
// ---------------------------------------------------------------------------
__global__ void __launch_bounds__(256) prep_kernel(
    const float* __restrict__ W1, const float* __restrict__ W2,
    _Float16* __restrict__ W1f, _Float16* __restrict__ W2f)
{
  int idx = blockIdx.x * 256 + threadIdx.x;   // grid 512 -> 0..131071
  int m  = idx >> 16;          // 0 -> W1, 1 -> W2
  int i2 = idx & 65535;
  int s = i2 & 7, lane = (i2 >> 3) & 63, ks = (i2 >> 9) & 7, ct = (i2 >> 12) & 15;
  int col = ct * 16 + (lane & 15);
  int k   = ks * 32 + (lane >> 4) * 8 + s;
  float v = (m == 0) ? W1[k * 256 + col] : W2[k * 256 + col];
  _Float16* dst = (m == 0) ? W1f : W2f;
  dst[i2] = (_Float16)v;
}

// ---------------------------------------------------------------------------
// Recurrence v4: 8 groups (32 rows) x 8 col-WGs. Each WG owns h-dims
// j*32..j*32+31 (all 4 gates). Wave (rt, e) owns rows rt*16.. and dims
// e*16+pc: gate tiles ct = 2q+e  ->  all 4 gates of a dim live in ONE lane
// -> LSTM epilogue fully in registers (c-state in VGPRs, no LDS epilogue).
// Exchange: self-validating tagged u32 (tag|f16) in ping-pong hx[t&1];
// consumers poll the data itself -> ONE MALL trip per step, no flags/fences.
// ---------------------------------------------------------------------------
__global__ void __launch_bounds__(256, 1) lstm_rec_kernel(
    const float* __restrict__ x, const float* __restrict__ Wx,
    const float* __restrict__ Wh, const float* __restrict__ bias,
    unsigned* __restrict__ hx, _Float16* __restrict__ h_all)
{
  __shared__ __align__(16) _Float16 Wt[8 * 12 * 64 * 8];   // 96 KB [ct][ks][lane][8]
  __shared__ __align__(16) _Float16 At[2 * 12 * 64 * 8];   // 24 KB [rt][ks][lane][8]

  const int tid = threadIdx.x;
  const int g  = blockIdx.x & 7;    // group (8 WGs of a group -> one XCD, perf only)
  const int j  = blockIdx.x >> 3;   // dim-owner 0..7 -> h dims j*32..j*32+31
  const int b0 = g * 32;

  // ---- one-time: weight slice 384 x 128 as f16 B-frags
  for (int idx = tid; idx < 384 * 128; idx += 256) {
    int k = idx >> 7, c = idx & 127;          // c = q*32 + d
    int q = c >> 5, d = c & 31;
    int gc = q * 256 + j * 32 + d;
    float v = (k < 128) ? Wx[k * 1024 + gc] : Wh[(k - 128) * 1024 + gc];
    int ct = c >> 4, lcol = c & 15;           // ct = 2q + (d>=16)
    int ks = k >> 5, kg = (k >> 3) & 3, s = k & 7;
    Wt[(((ct * 12 + ks) * 64) + kg * 16 + lcol) * 8 + s] = (_Float16)v;
  }

  const int lane = tid & 63, wid = tid >> 6;
  const int rt = wid & 1, e = wid >> 1;        // wave -> rows rt*16.., dim-half e
  const int prow = rt * 16 + ((lane >> 4) << 2);
  const int pc = lane & 15;
  const int gdim = j * 32 + e * 16 + pc;       // global h-dim this lane owns

  const float bv0 = bias[0 * 256 + gdim], bv1 = bias[1 * 256 + gdim],
              bv2 = bias[2 * 256 + gdim], bv3 = bias[3 * 256 + gdim];

  const int srow = tid >> 3, sseg = tid & 7;   // staging: 32 rows x 8 segs
  const int s_rt = srow >> 4, s_lrow = srow & 15;

  const float4* xb = (const float4*)x + (size_t)(b0 + srow) * 16384 + sseg * 4;
  float4 XR[4];
  XR[0] = xb[0]; XR[1] = xb[1]; XR[2] = xb[2]; XR[3] = xb[3];

  __syncthreads();   // Wt ready

  // ---- hoist B-frags: wave (rt,e) needs ct = 2q+e, q = 0..3, ks = 0..11
  half8 Bv[48];
  {
    const half8* Wp = (const half8*)Wt;
    #pragma unroll
    for (int q = 0; q < 4; ++q)
      #pragma unroll
      for (int ks = 0; ks < 12; ++ks)
        Bv[q * 12 + ks] = Wp[(2 * q + e) * 768 + ks * 64 + lane];
  }

  half8* Ag = (half8*)At;
  float cst[4] = {0.f, 0.f, 0.f, 0.f};         // c-state: 4 VGPRs, persistent
  f32x4 ax0, ax1, ax2, ax3;                    // x-part partial for next step

  // ---- pre-loop: stage x(0), x-part MFMA, prefetch x(1)
  {
    half8 p0, p1;
    p0[0] = (_Float16)XR[0].x; p0[1] = (_Float16)XR[0].y;
    p0[2] = (_Float16)XR[0].z; p0[3] = (_Float16)XR[0].w;
    p0[4] = (_Float16)XR[1].x; p0[5] = (_Float16)XR[1].y;
    p0[6] = (_Float16)XR[1].z; p0[7] = (_Float16)XR[1].w;
    p1[0] = (_Float16)XR[2].x; p1[1] = (_Float16)XR[2].y;
    p1[2] = (_Float16)XR[2].z; p1[3] = (_Float16)XR[2].w;
    p1[4] = (_Float16)XR[3].x; p1[5] = (_Float16)XR[3].y;
    p1[6] = (_Float16)XR[3].z; p1[7] = (_Float16)XR[3].w;
    int xi = (s_rt * 12 + (sseg >> 1)) * 64 + ((sseg & 1) * 2) * 16 + s_lrow;
    Ag[SWZ(xi)] = p0; Ag[SWZ(xi + 16)] = p1;
  }
  __syncthreads();
  {
    ax0 = (f32x4){0.f, 0.f, 0.f, 0.f}; ax1 = ax0; ax2 = ax0; ax3 = ax0;
    #pragma unroll
    for (int ks = 0; ks < 4; ++ks) {
      half8 av = Ag[SWZ(rt * 768 + ks * 64 + lane)];
      ax0 = __builtin_amdgcn_mfma_f32_16x16x32_f16(av, Bv[0 * 12 + ks], ax0, 0, 0, 0);
      ax1 = __builtin_amdgcn_mfma_f32_16x16x32_f16(av, Bv[1 * 12 + ks], ax1, 0, 0, 0);
      ax2 = __builtin_amdgcn_mfma_f32_16x16x32_f16(av, Bv[2 * 12 + ks], ax2, 0, 0, 0);
      ax3 = __builtin_amdgcn_mfma_f32_16x16x32_f16(av, Bv[3 * 12 + ks], ax3, 0, 0, 0);
    }
  }
  XR[0] = xb[32]; XR[1] = xb[33]; XR[2] = xb[34]; XR[3] = xb[35];

  for (int t = 0; t < 512; ++t) {
    // ---- stage h(t-1): poll directly on tagged data (tag == t), one MALL trip
    const int hbase = (s_rt * 12 + 4 + sseg) * 64 + s_lrow;
    if (t > 0) {
      const unsigned long long* hp = (const unsigned long long*)hx +
          (((t - 1) & 1) ? 32768 : 0) + (size_t)(b0 + srow) * 128 + sseg * 16;
      unsigned long long vv[16];
      const unsigned long long msk  = 0xFFFF0000FFFF0000ull;
      const unsigned long long want = ((unsigned long long)(unsigned)t << 16) |
                                      ((unsigned long long)(unsigned)t << 48);
      int iters = 0;
      while (true) {
        #pragma unroll
        for (int i = 0; i < 16; ++i) vv[i] = AL(hp + i);
        unsigned long long diff = 0;
        #pragma unroll
        for (int i = 0; i < 16; ++i) diff |= (vv[i] & msk) ^ want;
        if (diff == 0) break;
        if (++iters > (1 << 17)) break;   // valve: garbage instead of hang
      }
      H8U pk[4];
      #pragma unroll
      for (int i = 0; i < 16; ++i) {
        pk[i >> 2].s[(2 * i) & 7]     = (unsigned short)vv[i];
        pk[i >> 2].s[(2 * i + 1) & 7] = (unsigned short)(vv[i] >> 32);
      }
      #pragma unroll
      for (int kg = 0; kg < 4; ++kg) Ag[SWZ(hbase + kg * 16)] = pk[kg].v;
    } else {
      H8U zz; zz.u[0] = 0ull; zz.u[1] = 0ull;
      #pragma unroll
      for (int kg = 0; kg < 4; ++kg) Ag[SWZ(hbase + kg * 16)] = zz.v;
    }
    __syncthreads();   // S1: h frags ready

    // ---- h-part MFMA on top of precomputed x-part: 4 gate-chains of 8
    f32x4 a0 = ax0, a1 = ax1, a2 = ax2, a3 = ax3;
    #pragma unroll
    for (int ks = 4; ks < 12; ++ks) {
      half8 av = Ag[SWZ(rt * 768 + ks * 64 + lane)];
      a0 = __builtin_amdgcn_mfma_f32_16x16x32_f16(av, Bv[0 * 12 + ks], a0, 0, 0, 0);
      a1 = __builtin_amdgcn_mfma_f32_16x16x32_f16(av, Bv[1 * 12 + ks], a1, 0, 0, 0);
      a2 = __builtin_amdgcn_mfma_f32_16x16x32_f16(av, Bv[2 * 12 + ks], a2, 0, 0, 0);
      a3 = __builtin_amdgcn_mfma_f32_16x16x32_f16(av, Bv[3 * 12 + ks], a3, 0, 0, 0);
    }

    // ---- LSTM epilogue fully in registers (lane owns i,f,g,o of its dim)
    unsigned hw[4]; unsigned short hfb[4];
    #pragma unroll
    for (int r = 0; r < 4; ++r) {
      float iv = fast_sigmoid(a0[r] + bv0);
      float fv = fast_sigmoid(a1[r] + bv1);
      float gv = fast_tanh   (a2[r] + bv2);
      float ov = fast_sigmoid(a3[r] + bv3);
      cst[r] = fv * cst[r] + iv * gv;
      float hv = ov * fast_tanh(cst[r]);
      _Float16 hf = (_Float16)hv;
      unsigned short hb_; __builtin_memcpy(&hb_, &hf, 2);
      hfb[r] = hb_;
      hw[r] = ((unsigned)(t + 1) << 16) | (unsigned)hb_;
    }

    // ---- stage x(t+1) (tail work, off exchange path)
    if (t < 511) {
      half8 p0, p1;
      p0[0] = (_Float16)XR[0].x; p0[1] = (_Float16)XR[0].y;
      p0[2] = (_Float16)XR[0].z; p0[3] = (_Float16)XR[0].w;
      p0[4] = (_Float16)XR[1].x; p0[5] = (_Float16)XR[1].y;
      p0[6] = (_Float16)XR[1].z; p0[7] = (_Float16)XR[1].w;
      p1[0] = (_Float16)XR[2].x; p1[1] = (_Float16)XR[2].y;
      p1[2] = (_Float16)XR[2].z; p1[3] = (_Float16)XR[2].w;
      p1[4] = (_Float16)XR[3].x; p1[5] = (_Float16)XR[3].y;
      p1[6] = (_Float16)XR[3].z; p1[7] = (_Float16)XR[3].w;
      int xi = (s_rt * 12 + (sseg >> 1)) * 64 + ((sseg & 1) * 2) * 16 + s_lrow;
      Ag[SWZ(xi)] = p0; Ag[SWZ(xi + 16)] = p1;
    }
    __syncthreads();   // S2: x frags ready; At ks4-11 free for next staging

    // ---- stores AFTER S2: MALL write-ack overlaps the next poll
    {
      unsigned* hxp = hx + ((t & 1) ? 65536 : 0) + (size_t)(b0 + prow) * 256 + gdim;
      _Float16* hap = h_all + ((size_t)t * 256 + b0 + prow) * 256 + gdim;
      #pragma unroll
      for (int r = 0; r < 4; ++r) {
        AS(hxp + (size_t)r * 256, hw[r]);
        _Float16 hval; __builtin_memcpy(&hval, &hfb[r], 2);
        hap[(size_t)r * 256] = hval;
      }
    }

    // ---- x-part MFMA for t+1 + prefetch x(t+2) (fills the visibility window)
    if (t < 511) {
      ax0 = (f32x4){0.f, 0.f, 0.f, 0.f}; ax1 = ax0; ax2 = ax0; ax3 = ax0;
      #pragma unroll
      for (int ks = 0; ks < 4; ++ks) {
        half8 av = Ag[SWZ(rt * 768 + ks * 64 + lane)];
        ax0 = __builtin_amdgcn_mfma_f32_16x16x32_f16(av, Bv[0 * 12 + ks], ax0, 0, 0, 0);
        ax1 = __builtin_amdgcn_mfma_f32_16x16x32_f16(av, Bv[1 * 12 + ks], ax1, 0, 0, 0);
        ax2 = __builtin_amdgcn_mfma_f32_16x16x32_f16(av, Bv[2 * 12 + ks], ax2, 0, 0, 0);
        ax3 = __builtin_amdgcn_mfma_f32_16x16x32_f16(av, Bv[3 * 12 + ks], ax3, 0, 0, 0);
      }
      int tn = (t + 2 < 512) ? (t + 2) : 511;
      XR[0] = xb[(size_t)tn * 32 + 0]; XR[1] = xb[(size_t)tn * 32 + 1];
      XR[2] = xb[(size_t)tn * 32 + 2]; XR[3] = xb[(size_t)tn * 32 + 3];
    }
  }
}

// ---------------------------------------------------------------------------
// Head: per WG 64 rows of [T*B, H]; fused GEMM1->tanh->GEMM2->tanh->dot(W3).
// ---------------------------------------------------------------------------
__device__ __forceinline__ void head_gemm(const _Float16* __restrict__ A,
                                          const _Float16* __restrict__ Wf,
                                          const float* __restrict__ bvec,
                                          _Float16* __restrict__ Yd,
                                          int lane, int w)
{
  const half8* Af = (const half8*)A + w * 512 + lane;
  for (int ct = 0; ct < 16; ++ct) {
    const half8* Bf = (const half8*)Wf + ct * 512 + lane;
    f32x4 acc = {0.f, 0.f, 0.f, 0.f};
    #pragma unroll
    for (int ks = 0; ks < 8; ++ks)
      acc = __builtin_amdgcn_mfma_f32_16x16x32_f16(Af[ks * 64], Bf[ks * 64], acc, 0, 0, 0);
    int col = ct * 16 + (lane & 15);
    float bb = bvec[col];
    int ks2 = col >> 5, kg2 = (col >> 3) & 3, s2 = col & 7;
    #pragma unroll
    for (int r = 0; r < 4; ++r) {
      int row = w * 16 + ((lane >> 4) << 2) + r;
      float v = fast_tanh(acc[r] + bb);
      Yd[(((w * 8 + ks2) * 64) + kg2 * 16 + (row & 15)) * 8 + s2] = (_Float16)v;
    }
  }
}

__global__ void __launch_bounds__(256) head_kernel(
    const _Float16* __restrict__ h_all,
    const _Float16* __restrict__ W1f, const _Float16* __restrict__ W2f,
    const float* __restrict__ b1, const float* __restrict__ b2,
    const float* __restrict__ W3, const float* __restrict__ b3,
    float* __restrict__ out)
{
  __shared__ __align__(16) _Float16 A_s[16384];   // 32 KB
  __shared__ __align__(16) _Float16 Y_s[16384];   // 32 KB
  const int tid = threadIdx.x;
  const size_t r0 = (size_t)blockIdx.x * 64;

  {
    int row = tid >> 2, seg = tid & 3;
    int rtl = row >> 4, lrow = row & 15;
    const half8* hp = (const half8*)(h_all + (r0 + row) * 256 + seg * 64);
    #pragma unroll
    for (int i = 0; i < 8; ++i) {
      int k0 = seg * 64 + i * 8;
      int ks = k0 >> 5, kg = (k0 >> 3) & 3;
      ((half8*)A_s)[(rtl * 8 + ks) * 64 + kg * 16 + lrow] = hp[i];
    }
  }
  __syncthreads();

  const int lane = tid & 63, w = tid >> 6;
  head_gemm(A_s, W1f, b1, Y_s, lane, w);   // y1 = tanh(h @ W1 + b1)
  __syncthreads();
  head_gemm(Y_s, W2f, b2, A_s, lane, w);   // y2 = tanh(y1 @ W2 + b2)
  __syncthreads();

  {
    int row = tid >> 2, part = tid & 3;
    int rtl = row >> 4, lrow = row & 15;
    float p = 0.f;
    #pragma unroll
    for (int kk = 0; kk < 8; ++kk) {
      int k0 = part * 64 + kk * 8;
      int ks = k0 >> 5, kg = (k0 >> 3) & 3;
      half8 y = ((const half8*)A_s)[(rtl * 8 + ks) * 64 + kg * 16 + lrow];
      #pragma unroll
      for (int i = 0; i < 8; ++i) p += (float)y[i] * W3[k0 + i];
    }
    p += __shfl_xor(p, 1);
    p += __shfl_xor(p, 2);
    if (part == 0) {
      size_t r = r0 + row;                 // r = t*256 + b
      int tt = (int)(r >> 8), bb = (int)(r & 255);
      out[(size_t)bb * 512 + tt] = p + b3[0];
    }
  }
}

// ---------------------------------------------------------------------------
extern "C" void kernel_launch(void* const* d_in, const int* in_sizes, int n_in,
                              void* d_out, int out_size, void* d_ws, size_t ws_size,
                              hipStream_t stream)
{
  const float* x  = (const float*)d_in[0];
  const float* Wx = (const float*)d_in[1];
  const float* Wh = (const float*)d_in[2];
  const float* b  = (const float*)d_in[3];
  const float* W1 = (const float*)d_in[4];
  const float* b1 = (const float*)d_in[5];
  const float* W2 = (const float*)d_in[6];
  const float* b2 = (const float*)d_in[7];
  const float* W3 = (const float*)d_in[8];
  const float* b3 = (const float*)d_in[9];
  float* out = (float*)d_out;

  char* ws = (char*)d_ws;
  unsigned*  hx    = (unsigned*)ws;                        // ping-pong tagged h: 512 KB
  _Float16*  W1f   = (_Float16*)(ws + 524288);             // 128 KB
  _Float16*  W2f   = (_Float16*)(ws + 655360);             // 128 KB
  _Float16*  h_all = (_Float16*)(ws + 786432);             // [512][256][256] f16 = 64 MB
  if (ws_size < (size_t)786432 + 67108864) return;         // insufficient scratch

  hipMemsetAsync(hx, 0, 524288, stream);   // clear tags (fresh every replay)
  hipLaunchKernelGGL(prep_kernel, dim3(512), dim3(256), 0, stream,
                     W1, W2, W1f, W2f);
  hipLaunchKernelGGL(lstm_rec_kernel, dim3(64), dim3(256), 0, stream,
                     x, Wx, Wh, b, hx, h_all);
  hipLaunchKernelGGL(head_kernel, dim3(2048), dim3(256), 0, stream,
                     h_all, W1f, W2f, b1, b2, W3, b3, out);
}